// Round 1
// 192.059 us; speedup vs baseline: 1.0211x; 1.0211x over previous
//
#include <hip/hip_runtime.h>
#include <math.h>

#define Bx   32
#define Sx   1024
#define ATTx 512
#define ENCx 512

typedef float vfloat4 __attribute__((ext_vector_type(4)));
typedef float vfloat2 __attribute__((ext_vector_type(2)));

// tanh(x) = 1 - 2/(exp(2x)+1); exp2-based, saturates correctly at +-inf.
__device__ __forceinline__ float fast_tanh(float x) {
    float e = __builtin_amdgcn_exp2f(x * 2.8853900817779268f); // 2*log2(e)
    return fmaf(-2.0f, __builtin_amdgcn_rcpf(e + 1.0f), 1.0f);
}

__device__ __forceinline__ float tdot(vfloat4 k, float4 q, float4 v) {
    return fast_tanh(k.x + q.x) * v.x + fast_tanh(k.y + q.y) * v.y
         + fast_tanh(k.z + q.z) * v.z + fast_tanh(k.w + q.w) * v.w;
}

// ---------------------------------------------------------------------------
// Kernel A: qm/qc[b,a] = dot(dec_h[b,:], W[a,:]) + bias[a]   (wave per output)
// Dense loads: lane / lane+64 -> each dwordx4 instruction covers a contiguous
// 1 KB (was lane*2/lane*2+1 = 32B-stride, 50% density, 2x transactions).
// Extra block (blockIdx==8192) computes weight-normed v vectors.
// ---------------------------------------------------------------------------
__global__ __launch_bounds__(256) void precompute_kernel(
    const float* __restrict__ dec,
    const float* __restrict__ Wm, const float* __restrict__ bm,
    const float* __restrict__ Wc, const float* __restrict__ bc,
    const float* __restrict__ vm, const float* __restrict__ gm,
    const float* __restrict__ vc, const float* __restrict__ gc,
    float* __restrict__ qm, float* __restrict__ qc,
    float* __restrict__ vmn, float* __restrict__ vcn)
{
    if (blockIdx.x == 8192) {
        int t = threadIdx.x;
        int lane = t & 63, wid = t >> 6;
        float sm_ = 0.f, sc_ = 0.f;
        for (int i = t; i < ATTx; i += 256) {
            float a = vm[i]; sm_ += a * a;
            float c = vc[i]; sc_ += c * c;
        }
        #pragma unroll
        for (int off = 32; off; off >>= 1) {
            sm_ += __shfl_xor(sm_, off, 64);
            sc_ += __shfl_xor(sc_, off, 64);
        }
        __shared__ float wsm[4], wsc[4];
        if (lane == 0) { wsm[wid] = sm_; wsc[wid] = sc_; }
        __syncthreads();
        float nm = sqrtf(wsm[0] + wsm[1] + wsm[2] + wsm[3]);
        float nc = sqrtf(wsc[0] + wsc[1] + wsc[2] + wsc[3]);
        float sg_m = gm[0] / nm, sg_c = gc[0] / nc;
        for (int i = t; i < ATTx; i += 256) {
            vmn[i] = vm[i] * sg_m;
            vcn[i] = vc[i] * sg_c;
        }
        return;
    }
    int gw   = blockIdx.x * 4 + (threadIdx.x >> 6);  // 0..32767
    int lane = threadIdx.x & 63;
    int mat  = gw >> 14;           // 0: mono, 1: chunk
    int idx  = gw & 16383;
    int b = idx >> 9, a = idx & 511;
    const float4* W4 = (const float4*)((mat ? Wc : Wm) + (size_t)a * 512);
    const float4* d4 = (const float4*)(dec + (size_t)b * 512);
    float4 w0 = W4[lane], w1 = W4[lane + 64];
    float4 x0 = d4[lane], x1 = d4[lane + 64];
    float s = w0.x * x0.x + w0.y * x0.y + w0.z * x0.z + w0.w * x0.w
            + w1.x * x1.x + w1.y * x1.y + w1.z * x1.z + w1.w * x1.w;
    #pragma unroll
    for (int off = 32; off; off >>= 1) s += __shfl_xor(s, off, 64);
    if (lane == 0) {
        float bias = (mat ? bc : bm)[a];
        (mat ? qc : qm)[b * ATTx + a] = s + bias;
    }
}

// ---------------------------------------------------------------------------
// Kernel B: fused dual energy. One wave per (b, 4 consecutive s).
//  - q/v rows register-cached once per wave (L2 traffic 256MB -> 64MB)
//  - dense 1KB-per-instruction key loads (lane / lane+64), non-temporal
//  - 8 outstanding key loads per wave before any compute (MLP)
// ---------------------------------------------------------------------------
__global__ __launch_bounds__(256) void energy_kernel(
    const float* __restrict__ key,
    const float* __restrict__ qm, const float* __restrict__ qc,
    const float* __restrict__ vmn, const float* __restrict__ vcn,
    const float* __restrict__ vbm, const float* __restrict__ rm,
    const float* __restrict__ vbc, const float* __restrict__ rc,
    float* __restrict__ mono_e, float* __restrict__ chunk_e)
{
    int gw   = blockIdx.x * 4 + (threadIdx.x >> 6);   // 0..8191
    int lane = threadIdx.x & 63;
    int b     = gw >> 8;                // 256 s-groups per batch row
    int sbase = (gw & 255) << 2;        // 4 s per wave

    const float4* qm4 = (const float4*)(qm + (size_t)b * ATTx);
    const float4* qc4 = (const float4*)(qc + (size_t)b * ATTx);
    const float4* vm4 = (const float4*)vmn;
    const float4* vc4 = (const float4*)vcn;
    float4 qa0 = qm4[lane], qa1 = qm4[lane + 64];
    float4 qb0 = qc4[lane], qb1 = qc4[lane + 64];
    float4 va0 = vm4[lane], va1 = vm4[lane + 64];
    float4 vb0 = vc4[lane], vb1 = vc4[lane + 64];

    const vfloat4* k4 = (const vfloat4*)(key + ((size_t)b * Sx + sbase) * ATTx);
    vfloat4 k[8];
    #pragma unroll
    for (int ss = 0; ss < 4; ss++) {
        k[2 * ss]     = __builtin_nontemporal_load(k4 + (size_t)ss * 128 + lane);
        k[2 * ss + 1] = __builtin_nontemporal_load(k4 + (size_t)ss * 128 + lane + 64);
    }
    float em[4], ec[4];
    #pragma unroll
    for (int ss = 0; ss < 4; ss++) {
        em[ss] = tdot(k[2 * ss], qa0, va0) + tdot(k[2 * ss + 1], qa1, va1);
        ec[ss] = tdot(k[2 * ss], qb0, vb0) + tdot(k[2 * ss + 1], qb1, vb1);
    }
    #pragma unroll
    for (int off = 32; off; off >>= 1) {
        #pragma unroll
        for (int ss = 0; ss < 4; ss++) {
            em[ss] += __shfl_xor(em[ss], off, 64);
            ec[ss] += __shfl_xor(ec[ss], off, 64);
        }
    }
    if (lane == 0) {
        float cm = vbm[0] + rm[0], cc = vbc[0] + rc[0];
        size_t base = (size_t)b * Sx + sbase;
        #pragma unroll
        for (int ss = 0; ss < 4; ss++) {
            mono_e[base + ss]  = em[ss] + cm;
            chunk_e[base + ss] = ec[ss] + cc;
        }
    }
}

// ---------------------------------------------------------------------------
// Kernel C: per-row scans + moving windows. One block (1024 thr) per batch row.
// Also zeroes out[b,:] so the context kernel can accumulate atomically.
// ---------------------------------------------------------------------------
__global__ __launch_bounds__(1024) void scan_kernel(
    const float* __restrict__ mono_e, const float* __restrict__ chunk_e,
    const float* __restrict__ prev_att, const float* __restrict__ noise,
    float* __restrict__ beta, float* __restrict__ out)
{
    int b = blockIdx.x, t = threadIdx.x;       // t == s
    int lane = t & 63, wid = t >> 6;           // 16 waves
    __shared__ float wred[16];
    __shared__ float arrA[1024];
    __shared__ float arrB[1024];
    __shared__ float arrC[1024];

    if (t < ENCx) out[b * ENCx + t] = 0.0f;    // zero context accumulator

    size_t base = (size_t)b * Sx;
    float pa = prev_att[base + t];

    // ---- row sum of prev_att ----
    float sum = pa;
    #pragma unroll
    for (int off = 32; off; off >>= 1) sum += __shfl_xor(sum, off, 64);
    if (lane == 0) wred[wid] = sum;
    __syncthreads();
    float psum = 0.f;
    #pragma unroll
    for (int i = 0; i < 16; i++) psum += wred[i];

    // ---- p_sel ----
    float me = mono_e[base + t], nz = noise[base + t];
    float p = 1.0f / (1.0f + expf(-(me + nz)));
    if (t == Sx - 1) p = 1.0f;
    float om = 1.0f - p;

    // ---- exclusive cumprod of (1-p): wave inclusive scan + cross-wave ----
    float v = om;
    #pragma unroll
    for (int d = 1; d < 64; d <<= 1) {
        float tv = __shfl_up(v, d, 64);
        if (lane >= d) v *= tv;
    }
    __syncthreads();                       // psum reads of wred done
    if (lane == 63) wred[wid] = v;
    __syncthreads();
    float pre = 1.0f;
    for (int i = 0; i < wid; i++) pre *= wred[i];
    float incp = pre * v;                  // inclusive cumprod at t
    arrA[t] = incp;
    __syncthreads();
    float cp = (t == 0) ? 1.0f : arrA[t - 1];   // exclusive

    // ---- inclusive cumsum of prev_norm / clip(cp) ----
    float cpc = fminf(fmaxf(cp, 1e-20f), 1.0f);
    float y = (pa / psum) / cpc;
    float w2 = y;
    #pragma unroll
    for (int d = 1; d < 64; d <<= 1) {
        float tv = __shfl_up(w2, d, 64);
        if (lane >= d) w2 += tv;
    }
    __syncthreads();                       // arrA[t-1] reads done, wred reads done
    if (lane == 63) wred[wid] = w2;
    __syncthreads();
    float pres = 0.f;
    for (int i = 0; i < wid; i++) pres += wred[i];
    float cs = pres + w2;
    float alpha = p * cp * cs;

    // ---- chunk energy windows (w = 8) ----
    float ce = chunk_e[base + t];
    arrA[t] = ce;                          // safe: all arrA reads happened before barriers above
    __syncthreads();
    float mx = ce;
    #pragma unroll
    for (int j = 1; j < 8; j++) { int i2 = t - j; if (i2 >= 0) mx = fmaxf(mx, arrA[i2]); }
    float eu = expf(ce - mx);
    arrB[t] = eu;
    __syncthreads();
    float den = eu;
    #pragma unroll
    for (int j = 1; j < 8; j++) { int i2 = t - j; if (i2 >= 0) den += arrB[i2]; }
    den = fmaxf(den, 1e-10f);
    arrC[t] = alpha / den;
    __syncthreads();
    float acc = 0.f;
    #pragma unroll
    for (int j = 0; j < 8; j++) { int i2 = t + j; if (i2 < Sx) acc += arrC[i2]; }
    beta[base + t] = eu * acc;
}

// ---------------------------------------------------------------------------
// Kernel D: context[b,d] = sum_s beta[b,s] * value[b,s,d]
// grid = B*16 blocks, each covers 64 s-positions, full d.
// 16 B/lane dwordx4 loads; waves 0/1 stream even s, waves 2/3 odd s (two
// independent row streams in flight). LDS-combine halves atomics vs per-wave.
// beta[s] is wave-uniform per iteration -> s_load. value non-temporal.
// ---------------------------------------------------------------------------
__global__ __launch_bounds__(256) void context_kernel(
    const float* __restrict__ beta, const float* __restrict__ value,
    float* __restrict__ out)
{
    int blk = blockIdx.x;
    int b = blk >> 4, chunk = blk & 15;
    int s0 = chunk * 64;
    int t = threadIdx.x;
    int d4i = t & 127;                    // float4 index: d = 4*d4i
    int sp  = t >> 7;                     // s parity: 0 or 1
    const vfloat4* v4 = (const vfloat4*)(value + ((size_t)(b * Sx + s0 + sp)) * ENCx) + d4i;
    const float*   bp = beta + (size_t)b * Sx + s0 + sp;
    float ax = 0.f, ay = 0.f, az = 0.f, aw = 0.f;
    #pragma unroll 8
    for (int i = 0; i < 32; i++) {
        float w = bp[2 * i];                                 // wave-uniform -> s_load
        vfloat4 vv = __builtin_nontemporal_load(v4 + (size_t)(2 * i) * (ENCx / 4));
        ax = fmaf(w, vv.x, ax);
        ay = fmaf(w, vv.y, ay);
        az = fmaf(w, vv.z, az);
        aw = fmaf(w, vv.w, aw);
    }
    __shared__ vfloat4 part[128];
    if (sp) { vfloat4 pv = {ax, ay, az, aw}; part[d4i] = pv; }
    __syncthreads();
    if (!sp) {
        vfloat4 pv = part[d4i];
        float* o = out + b * ENCx + 4 * d4i;
        atomicAdd(o + 0, ax + pv.x);
        atomicAdd(o + 1, ay + pv.y);
        atomicAdd(o + 2, az + pv.z);
        atomicAdd(o + 3, aw + pv.w);
    }
}

// ---------------------------------------------------------------------------
extern "C" void kernel_launch(void* const* d_in, const int* in_sizes, int n_in,
                              void* d_out, int out_size, void* d_ws, size_t ws_size,
                              hipStream_t stream) {
    const float* dec      = (const float*)d_in[0];
    const float* key      = (const float*)d_in[1];
    const float* value    = (const float*)d_in[2];
    const float* prev_att = (const float*)d_in[3];
    const float* noise    = (const float*)d_in[4];
    const float* Wm  = (const float*)d_in[5];
    const float* bm  = (const float*)d_in[6];
    const float* vm  = (const float*)d_in[7];
    const float* gm  = (const float*)d_in[8];
    const float* vbm = (const float*)d_in[9];
    const float* rm  = (const float*)d_in[10];
    const float* Wc  = (const float*)d_in[11];
    const float* bc  = (const float*)d_in[12];
    const float* vc  = (const float*)d_in[13];
    const float* gc  = (const float*)d_in[14];
    const float* vbc = (const float*)d_in[15];
    const float* rc  = (const float*)d_in[16];
    float* out = (float*)d_out;

    float* ws      = (float*)d_ws;
    float* qm      = ws;                   // [B,ATT]   16384
    float* qc      = qm + Bx * ATTx;       // 16384
    float* vmn     = qc + Bx * ATTx;       // 512
    float* vcn     = vmn + ATTx;           // 512
    float* mono_e  = vcn + ATTx;           // [B,S] 32768
    float* chunk_e = mono_e + Bx * Sx;     // 32768
    float* beta    = chunk_e + Bx * Sx;    // 32768

    precompute_kernel<<<8193, 256, 0, stream>>>(dec, Wm, bm, Wc, bc, vm, gm, vc, gc,
                                                qm, qc, vmn, vcn);
    energy_kernel<<<2048, 256, 0, stream>>>(key, qm, qc, vmn, vcn,
                                            vbm, rm, vbc, rc, mono_e, chunk_e);
    scan_kernel<<<Bx, 1024, 0, stream>>>(mono_e, chunk_e, prev_att, noise, beta, out);
    context_kernel<<<Bx * 16, 256, 0, stream>>>(beta, value, out);
}